// Round 1
// 1326.156 us; speedup vs baseline: 1.1147x; 1.1147x over previous
//
#include <hip/hip_runtime.h>
#include <math.h>

#define Bn 64
#define Sn 512
#define Zn 1024
#define H1n 512
#define H2n 256
#define ZSn (Zn*Sn)

// workspace float offsets
#define OFF_LP1  0          // 1024
#define OFF_VT   1024       // 256*64  (V transposed [h][b], f32 — fallback gemm)
#define OFF_V    17408      // 64*512
#define OFF_W    50176      // 64*512
#define OFF_R    82944      // 64*1024
#define OFF_PM   148480     // 64*16*512
#define OFF_PS   672768     // 64*16*512
#define OFF_VB   1200128    // bf16 V [b][h], 16384 ushorts = 8192 floats (fits in PS..KB gap)
#define OFF_KB   1310720    // bf16 K (as ushort), 33.5M elems = 64 MB
#define NEED_BF16_BYTES ((size_t)OFF_KB*4 + (size_t)Bn*ZSn*2)

#define NINF (-__builtin_inff())

typedef __attribute__((ext_vector_type(8))) short          s16x8;
typedef __attribute__((ext_vector_type(8))) unsigned short u16x8;
typedef __attribute__((ext_vector_type(4))) float          f32x4;

__device__ __forceinline__ float wred_max(float x){
#pragma unroll
  for (int o=32;o;o>>=1) x = fmaxf(x, __shfl_xor(x, o, 64));
  return x;
}
__device__ __forceinline__ float wred_sum(float x){
#pragma unroll
  for (int o=32;o;o>>=1) x += __shfl_xor(x, o, 64);
  return x;
}
__device__ __forceinline__ float lae(float a, float c){
  float m = fmaxf(a,c), n = fminf(a,c);
  return m + log1pf(__expf(n-m));
}
__device__ __forceinline__ float toF(float v){ return v; }
__device__ __forceinline__ float toF(unsigned short v){ return __uint_as_float(((unsigned int)v)<<16); }
__device__ __forceinline__ unsigned short bf16rne(float f){
  unsigned int u = __float_as_uint(f);
  return (unsigned short)((u + 0x7fffu + ((u>>16)&1u)) >> 16);
}
__device__ __forceinline__ unsigned int pack2(float a, float b){
  unsigned int ua = __float_as_uint(a), ub = __float_as_uint(b);
  ua = (ua + 0x7fffu + ((ua>>16)&1u)) >> 16;
  ub = (ub + 0x7fffu + ((ub>>16)&1u)) & 0xffff0000u;
  return ua | ub;
}

// single block: lp1 = log_softmax(prior)
__global__ __launch_bounds__(512) void prep_kernel(const float* __restrict__ prior,
                                                   float* __restrict__ ws){
  __shared__ float red[8];
  int t = threadIdx.x;
  float x0 = prior[t], x1 = prior[t+512];
  float m = wred_max(fmaxf(x0,x1));
  if ((t&63)==0) red[t>>6] = m;
  __syncthreads();
  float M = red[0];
#pragma unroll
  for (int i=1;i<8;i++) M = fmaxf(M, red[i]);
  float e = __expf(x0-M)+__expf(x1-M);
  e = wred_sum(e);
  __syncthreads();
  if ((t&63)==0) red[t>>6] = e;
  __syncthreads();
  float T = 0.f;
#pragma unroll
  for (int i=0;i<8;i++) T += red[i];
  float lse = M + logf(T);
  ws[OFF_LP1 + t]       = x0 - lse;
  ws[OFF_LP1 + t + 512] = x1 - lse;
}

// one block per batch: softmax -> sigmoid MLP -> VT[h][b] f32 (+ bf16 V[b][h] if wbf)
__global__ __launch_bounds__(512) void mlp_kernel(const float* __restrict__ sl,
    const float* __restrict__ W1, const float* __restrict__ b1,
    const float* __restrict__ W2, const float* __restrict__ b2,
    float* __restrict__ ws, int wbf){
  __shared__ float p[Sn];
  __shared__ float h1s[H1n];
  __shared__ float red[8];
  int b = blockIdx.x, t = threadIdx.x;
  float x = sl[b*Sn + t];
  float m = wred_max(x);
  if ((t&63)==0) red[t>>6] = m;
  __syncthreads();
  float M = red[0];
#pragma unroll
  for (int i=1;i<8;i++) M = fmaxf(M, red[i]);
  float e = __expf(x-M);
  float es = wred_sum(e);
  __syncthreads();
  if ((t&63)==0) red[t>>6] = es;
  __syncthreads();
  float T = 0.f;
#pragma unroll
  for (int i=0;i<8;i++) T += red[i];
  p[t] = e / T;
  __syncthreads();
  float acc = b1[t];
#pragma unroll 8
  for (int s=0;s<Sn;s++) acc = fmaf(p[s], W1[s*H1n + t], acc);
  h1s[t] = 1.f/(1.f+__expf(-acc));
  __syncthreads();
  if (t < H2n){
    float a2 = b2[t];
#pragma unroll 8
    for (int s=0;s<H1n;s++) a2 = fmaf(h1s[s], W2[s*H2n + t], a2);
    float vv = 1.f/(1.f+__expf(-a2));
    ws[OFF_VT + t*Bn + b] = vv;
    if (wbf) ((unsigned short*)(ws + OFF_VB))[b*H2n + t] = bf16rne(vv);
  }
}

// ---------------- fallback f32 gemm (ws too small for bf16 K) ----------------
template<int BF>
__global__ __launch_bounds__(256,1) void gemm_kernel(const float* __restrict__ Wout,
    const float* __restrict__ bout, const float* __restrict__ ws,
    float* __restrict__ Kf, unsigned int* __restrict__ Kb){
  int zh = blockIdx.x*256 + threadIdx.x;
  const float* __restrict__ VT = ws + OFF_VT;
  float2 acc[Bn];
#pragma unroll
  for (int b=0;b<Bn;b++){ acc[b].x = 0.f; acc[b].y = 0.f; }
  const float2* Wp = (const float2*)Wout;
#pragma unroll 2
  for (int h=0; h<H2n; h++){
    float2 wv = Wp[(size_t)h*(ZSn/2) + zh];
    const float* vh = VT + (h<<6);
#pragma unroll
    for (int b=0;b<Bn;b++){
      acc[b].x = fmaf(vh[b], wv.x, acc[b].x);
      acc[b].y = fmaf(vh[b], wv.y, acc[b].y);
    }
  }
  float2 bb = ((const float2*)bout)[zh];
#pragma unroll
  for (int b=0;b<Bn;b++){
    float ax = acc[b].x + bb.x, ay = acc[b].y + bb.y;
    if (BF){
      Kb[(size_t)b*(ZSn/2) + zh] = pack2(ax, ay);
    } else {
      float2 o; o.x = ax; o.y = ay;
      ((float2*)Kf)[(size_t)b*(ZSn/2) + zh] = o;
    }
  }
}

// ---------------- MFMA gemm: K[b,zs] = sum_h V[b,h]*Wout[h,zs] + bout[zs] ----
// A = V [64 x 256] bf16 (LDS-resident), B = Wout tile [32 x 64] f32 staged ->
// converted to bf16 in-flight (v_cvt_pk_bf16_f32), 16x16x32 MFMA, K = h.
// Block: 64 zs cols, 4 waves (one 16-col n-tile each), all 64 batches, 8 k-steps.
__global__ __launch_bounds__(256,3) void gemm_mfma(const float* __restrict__ Wout,
    const float* __restrict__ bout, const float* __restrict__ ws,
    unsigned short* __restrict__ Kb){
  __shared__ unsigned short Vsh[64*264];   // [b][h] bf16, row pad +8 (bank spread)
  __shared__ float Bsh[32*65];             // [hh][n] f32, row pad +1
  int t = threadIdx.x;
  int zs0 = blockIdx.x * 64;

  // stage V (bf16, 32 KB logical) into padded LDS
  {
    const unsigned short* vsrc = (const unsigned short*)(ws + OFF_VB);
    int vrow = t >> 2, vq = t & 3;
#pragma unroll
    for (int i=0;i<8;i++)
      *(u16x8*)&Vsh[vrow*264 + vq*64 + i*8] = *(const u16x8*)&vsrc[vrow*256 + vq*64 + i*8];
  }

  int w  = t >> 6;          // wave id -> n-tile
  int l  = t & 63;
  int q  = l & 15;          // n within tile (B) / m within tile (A) / D col
  int kg = l >> 4;          // k-group
  int sh = t >> 3, sf = t & 7;   // staging: h-row, float4 slot

  float bo = bout[zs0 + (w<<4) + q];

  f32x4 acc[4] = {{0.f,0.f,0.f,0.f},{0.f,0.f,0.f,0.f},{0.f,0.f,0.f,0.f},{0.f,0.f,0.f,0.f}};

  // prefetch k-step 0
  const float4* src = (const float4*)(Wout + (size_t)sh * ZSn + zs0);
  float4 ra = src[sf], rb = src[sf+8];

  for (int ks=0; ks<8; ks++){
    __syncthreads();                       // Bsh free (and Vsh ready at ks=0)
    {
      float* drow = &Bsh[sh*65 + (sf<<2)];
      drow[0]=ra.x; drow[1]=ra.y; drow[2]=ra.z; drow[3]=ra.w;
      drow[32]=rb.x; drow[33]=rb.y; drow[34]=rb.z; drow[35]=rb.w;
    }
    if (ks < 7){
      const float4* s2 = (const float4*)(Wout + (size_t)((ks+1)*32 + sh) * ZSn + zs0);
      ra = s2[sf]; rb = s2[sf+8];          // in flight across compute
    }
    __syncthreads();                       // Bsh ready
    // B fragment: 8 f32 along h at fixed n, convert->bf16 (RNE) packed
    float bf[8];
#pragma unroll
    for (int j=0;j<8;j++) bf[j] = Bsh[(kg*8+j)*65 + (w<<4) + q];
    unsigned int pk[4];
#pragma unroll
    for (int j=0;j<4;j++)
      asm("v_cvt_pk_bf16_f32 %0, %1, %2" : "=v"(pk[j]) : "v"(bf[2*j]), "v"(bf[2*j+1]));
    union { unsigned int u[4]; s16x8 v; } bu;
    bu.u[0]=pk[0]; bu.u[1]=pk[1]; bu.u[2]=pk[2]; bu.u[3]=pk[3];
    // A fragments (same k mapping: h = ks*32 + kg*8 + j) + 4 MFMAs (all batches)
#pragma unroll
    for (int mt=0; mt<4; mt++){
      s16x8 af = *(const s16x8*)&Vsh[(mt*16 + q)*264 + ks*32 + kg*8];
      acc[mt] = __builtin_amdgcn_mfma_f32_16x16x32_bf16(af, bu.v, acc[mt], 0, 0, 0);
    }
  }
  // D layout: col = lane&15, row = (lane>>4)*4 + reg  [verified m89/m91]
#pragma unroll
  for (int mt=0; mt<4; mt++){
#pragma unroll
    for (int r=0; r<4; r++){
      int b = mt*16 + kg*4 + r;
      Kb[(size_t)b*ZSn + zs0 + (w<<4) + q] = bf16rne(acc[mt][r] + bo);
    }
  }
}

// Fused sinkhorn iteration: block = (batch b, 64-row chunk c).
template<typename KT>
__global__ __launch_bounds__(512) void iter_fused(const KT* __restrict__ Kg,
    float* __restrict__ ws, const float* __restrict__ sl, int iter, int mode){
  __shared__ KT Ksh[64*512];
  __shared__ float vsh[512];
  __shared__ float ush[64];
  __shared__ float lsh[64];
  int t = threadIdx.x;
  int b = blockIdx.x >> 4, c = blockIdx.x & 15;
  const float4* s4 = (const float4*)(Kg + ((size_t)((b<<10) + (c<<6)) << 9));
  float4* d4 = (float4*)Ksh;
  constexpr int NV = (int)sizeof(KT)*4;
#pragma unroll
  for (int i=0;i<NV;i++) d4[i*512 + t] = s4[i*512 + t];
  if (t < 64) lsh[t] = ws[OFF_LP1 + (c<<6) + t];
  float v_s;
  if (iter == 0) v_s = 0.f;
  else {
    float M = NINF, S = 0.f;
#pragma unroll
    for (int cc=0; cc<16; cc++){
      float m = ws[OFF_PM + ((b*16+cc)<<9) + t];
      float p = ws[OFF_PS + ((b*16+cc)<<9) + t];
      float nm = fmaxf(M, m);
      S = S*__expf(M-nm) + p*__expf(m-nm);
      M = nm;
    }
    v_s = sl[(b<<9) + t] - (M + logf(S));
  }
  vsh[t] = v_s;
  if (mode) ws[OFF_V + (b<<9) + t] = v_s;
  __syncthreads();
  // row phase: 8 waves x 8 rows; lane owns 8 CONTIGUOUS cols -> 1 ds_read_b128
  int l = t & 63, w = t >> 6;
  float vr[8];
#pragma unroll
  for (int j=0;j<8;j++) vr[j] = vsh[(l<<3)+j];
#pragma unroll
  for (int rr=0; rr<8; rr++){
    int row = (w<<3) + rr;
    float x[8];
    if constexpr (sizeof(KT)==2){
      u16x8 kv = *(const u16x8*)&Ksh[(row<<9) + (l<<3)];
#pragma unroll
      for (int j=0;j<8;j++) x[j] = toF((unsigned short)kv[j]) + vr[j];
    } else {
      const float4* kp = (const float4*)&Ksh[(row<<9) + (l<<3)];
      float4 k0 = kp[0], k1 = kp[1];
      x[0]=k0.x+vr[0]; x[1]=k0.y+vr[1]; x[2]=k0.z+vr[2]; x[3]=k0.w+vr[3];
      x[4]=k1.x+vr[4]; x[5]=k1.y+vr[5]; x[6]=k1.z+vr[6]; x[7]=k1.w+vr[7];
    }
    float m = NINF;
#pragma unroll
    for (int j=0;j<8;j++) m = fmaxf(m, x[j]);
    m = wred_max(m);
    float s = 0.f;
#pragma unroll
    for (int j=0;j<8;j++) s += __expf(x[j]-m);
    s = wred_sum(s);
    float L = m + logf(s);
    if (l == 0){
      ush[row] = lsh[row] - L;
      if (mode) ws[OFF_R + (b<<10) + (c<<6) + row] = L;
    }
  }
  __syncthreads();
  // col phase: 2 independent online-LSE chains (halves the dependent latency)
  float M0 = NINF, S0 = 0.f, M1 = NINF, S1 = 0.f;
#pragma unroll 8
  for (int i=0;i<32;i++){
    float xa = toF(Ksh[(i<<9) + t]) + ush[i];
    float na = fmaxf(M0, xa);
    S0 = S0*__expf(M0-na) + __expf(xa-na);
    M0 = na;
    float xb = toF(Ksh[((i+32)<<9) + t]) + ush[i+32];
    float nb = fmaxf(M1, xb);
    S1 = S1*__expf(M1-nb) + __expf(xb-nb);
    M1 = nb;
  }
  float M = fmaxf(M0, M1);
  float S = S0*__expf(M0-M) + S1*__expf(M1-M);
  ws[OFF_PM + ((b*16+c)<<9) + t] = M;
  ws[OFF_PS + ((b*16+c)<<9) + t] = S;
}

// combine partials -> L_col; accept_raw = lp2 - v - L_col; w = v + accept_raw - max
__global__ __launch_bounds__(512) void wker(float* __restrict__ ws, const float* __restrict__ sl){
  __shared__ float red[8];
  int b = blockIdx.x, s = threadIdx.x;
  float M = NINF, S = 0.f;
#pragma unroll
  for (int cc=0; cc<16; cc++){
    float m = ws[OFF_PM + ((b*16+cc)<<9) + s];
    float p = ws[OFF_PS + ((b*16+cc)<<9) + s];
    float nm = fmaxf(M, m);
    S = S*__expf(M-nm) + p*__expf(m-nm);
    M = nm;
  }
  float L = M + logf(S);
  float v = ws[OFF_V + (b<<9) + s];
  float araw = sl[(b<<9)+s] - v - L;
  float mm = wred_max(araw);
  if ((s&63)==0) red[s>>6] = mm;
  __syncthreads();
  float amax = red[0];
#pragma unroll
  for (int i=1;i<8;i++) amax = fmaxf(amax, red[i]);
  ws[OFF_W + (b<<9) + s] = v + araw - amax;
}

// fused resample + output: wave per row, lane owns 8 contiguous cols.
template<typename KT>
__global__ __launch_bounds__(512) void final_fused(const KT* __restrict__ Kg,
    float* __restrict__ out, const float* __restrict__ ws, const float* __restrict__ sl){
  int t = threadIdx.x, l = t & 63, wv = t >> 6;
  int row = blockIdx.x*8 + wv;
  int b = row >> 10, z = row & (Zn-1);
  const KT* Kr = Kg + ((size_t)row << 9);
  const float* wr = ws + OFF_W + (b << 9);
  const float* pr = sl + (b << 9);
  float r  = ws[OFF_R + row];
  float l1 = ws[OFF_LP1 + z];
  float ww[8], pp[8], kk[8];
  {
    const float4* wp = (const float4*)(wr + (l<<3));
    float4 w0 = wp[0], w1 = wp[1];
    ww[0]=w0.x; ww[1]=w0.y; ww[2]=w0.z; ww[3]=w0.w;
    ww[4]=w1.x; ww[5]=w1.y; ww[6]=w1.z; ww[7]=w1.w;
    const float4* pt = (const float4*)(pr + (l<<3));
    float4 p0 = pt[0], p1 = pt[1];
    pp[0]=p0.x; pp[1]=p0.y; pp[2]=p0.z; pp[3]=p0.w;
    pp[4]=p1.x; pp[5]=p1.y; pp[6]=p1.z; pp[7]=p1.w;
  }
  if constexpr (sizeof(KT)==2){
    u16x8 kv = *(const u16x8*)&Kr[l<<3];
#pragma unroll
    for (int j=0;j<8;j++) kk[j] = toF((unsigned short)kv[j]);
  } else {
    const float4* kp = (const float4*)&Kr[l<<3];
    float4 k0 = kp[0], k1 = kp[1];
    kk[0]=k0.x; kk[1]=k0.y; kk[2]=k0.z; kk[3]=k0.w;
    kk[4]=k1.x; kk[5]=k1.y; kk[6]=k1.z; kk[7]=k1.w;
  }
  float a[8], m = NINF;
#pragma unroll
  for (int j=0;j<8;j++){
    a[j] = kk[j] - r + ww[j];
    m = fmaxf(m, a[j]);
  }
  m = wred_max(m);
  float s = 0.f;
#pragma unroll
  for (int j=0;j<8;j++) s += __expf(a[j]-m);
  s = wred_sum(s);
  float lk = m + logf(s);
  float rs = (lk >= 0.f) ? NINF : log1pf(-__expf(lk));
  float o[8];
#pragma unroll
  for (int j=0;j<8;j++) o[j] = l1 + lae(a[j], rs + pp[j]);
  float4 o0, o1;
  o0.x=o[0]; o0.y=o[1]; o0.z=o[2]; o0.w=o[3];
  o1.x=o[4]; o1.y=o[5]; o1.z=o[6]; o1.w=o[7];
  float4* op = (float4*)(out + ((size_t)row << 9) + (l<<3));
  op[0] = o0; op[1] = o1;
}

extern "C" void kernel_launch(void* const* d_in, const int* in_sizes, int n_in,
                              void* d_out, int out_size, void* d_ws, size_t ws_size,
                              hipStream_t stream) {
  const float* sl    = (const float*)d_in[0];
  const float* W1    = (const float*)d_in[1];
  const float* b1    = (const float*)d_in[2];
  const float* W2    = (const float*)d_in[3];
  const float* b2    = (const float*)d_in[4];
  const float* Wout  = (const float*)d_in[5];
  const float* bout  = (const float*)d_in[6];
  const float* prior = (const float*)d_in[7];
  float* ws = (float*)d_ws;
  float* Kf = (float*)d_out;
  unsigned short* Kb = (unsigned short*)(ws + OFF_KB);
  const bool use_bf16 = (ws_size >= NEED_BF16_BYTES);

  prep_kernel<<<1, 512, 0, stream>>>(prior, ws);
  mlp_kernel<<<Bn, 512, 0, stream>>>(sl, W1, b1, W2, b2, ws, use_bf16 ? 1 : 0);

  if (use_bf16){
    gemm_mfma<<<ZSn/64, 256, 0, stream>>>(Wout, bout, ws, Kb);
    for (int it = 0; it < 10; ++it)
      iter_fused<unsigned short><<<Bn*16, 512, 0, stream>>>(Kb, ws, sl, it, 0);
    iter_fused<unsigned short><<<Bn*16, 512, 0, stream>>>(Kb, ws, sl, 10, 1);
    wker<<<Bn, 512, 0, stream>>>(ws, sl);
    final_fused<unsigned short><<<Bn*Zn/8, 512, 0, stream>>>(Kb, (float*)d_out, ws, sl);
  } else {
    gemm_kernel<0><<<ZSn/512, 256, 0, stream>>>(Wout, bout, ws, Kf, nullptr);
    for (int it = 0; it < 10; ++it)
      iter_fused<float><<<Bn*16, 512, 0, stream>>>(Kf, ws, sl, it, 0);
    iter_fused<float><<<Bn*16, 512, 0, stream>>>(Kf, ws, sl, 10, 1);
    wker<<<Bn, 512, 0, stream>>>(ws, sl);
    final_fused<float><<<Bn*Zn/8, 512, 0, stream>>>(Kf, (float*)d_out, ws, sl);
  }
}